// Round 1
// baseline (28379.868 us; speedup 1.0000x reference)
//
#include <hip/hip_runtime.h>
#include <hip/hip_bf16.h>

// Problem: B=64, T=1024, D=512, F=512, all fp32.
// out = scan over t of h = tanh(x@W_ih + bias + h_prev@W_hh), return_sequences.
//
// Plan:
//  K1: x_proj GEMM [65536,512]@[512,512]+bias -> written into d_out (acts as xp buffer,
//      overwritten in-place by the scan, each slot read exactly once before overwrite).
//  K2: persistent scan. 256 blocks x 256 threads. Block (g = row 0..63, s = slice 0..3)
//      holds W_hh[:, 128s:128s+128] in REGISTERS (256 VGPR/thread). Per step: group of
//      4 blocks exchanges h[g,:] (2 KB) through a double-buffered global buffer with a
//      monotonic per-row flag counter (device-scope atomics + agent fences; L2s are not
//      cross-XCD coherent so the coherence point is L3).
//      >256 VGPR/thread forces 1 block/CU, so 256 blocks on 256 CUs are all co-resident
//      (a CU cannot host 2 of these blocks) -> spin-wait cannot deadlock.

#define RNN_B 64
#define RNN_T 1024
#define RNN_D 512
#define RNN_F 512

// ---------------------------------------------------------------------------
// Kernel 1: x_proj = X @ W_ih + bias.  M=65536 (b*T+t), N=512, K=512.
// 128x128 tile, K-tile 16, 8x8 per thread, single-buffered LDS.
// ---------------------------------------------------------------------------
__global__ __launch_bounds__(256) void xproj_gemm(
    const float* __restrict__ A,     // [65536, 512]
    const float* __restrict__ W,     // [512, 512]
    const float* __restrict__ bias,  // [512]
    float* __restrict__ C)           // [65536, 512]
{
    __shared__ float As[16][132];  // [k][m], padded pitch
    __shared__ float Bs[16][132];  // [k][n]

    const int tid = threadIdx.x;
    const int bid = blockIdx.x;
    const int mt = bid >> 2;
    const int nt = bid & 3;
    const size_t M0 = (size_t)mt * 128;
    const int N0 = nt * 128;

    const int tm = tid >> 4;   // 0..15
    const int tn = tid & 15;   // 0..15

    // staging maps
    const int ar = tid >> 2;          // 0..63 (A rows, +64 second pass)
    const int ac = (tid & 3) * 4;     // k offset within tile
    const int br = tid >> 5;          // 0..7  (B k-rows, +8 second pass)
    const int bc = (tid & 31) * 4;    // n offset

    float acc[8][8];
    #pragma unroll
    for (int i = 0; i < 8; ++i)
        #pragma unroll
        for (int jx = 0; jx < 8; ++jx) acc[i][jx] = 0.f;

    float bv[8];
    #pragma unroll
    for (int i = 0; i < 8; ++i) bv[i] = bias[N0 + tn * 8 + i];

    for (int k0 = 0; k0 < 512; k0 += 16) {
        float4 a0 = *(const float4*)(A + (M0 + ar) * 512 + k0 + ac);
        float4 a1 = *(const float4*)(A + (M0 + ar + 64) * 512 + k0 + ac);
        float4 b0 = *(const float4*)(W + (size_t)(k0 + br) * 512 + N0 + bc);
        float4 b1 = *(const float4*)(W + (size_t)(k0 + br + 8) * 512 + N0 + bc);
        __syncthreads();
        As[ac + 0][ar] = a0.x; As[ac + 1][ar] = a0.y;
        As[ac + 2][ar] = a0.z; As[ac + 3][ar] = a0.w;
        As[ac + 0][ar + 64] = a1.x; As[ac + 1][ar + 64] = a1.y;
        As[ac + 2][ar + 64] = a1.z; As[ac + 3][ar + 64] = a1.w;
        *(float4*)&Bs[br][bc]     = b0;
        *(float4*)&Bs[br + 8][bc] = b1;
        __syncthreads();
        #pragma unroll
        for (int kk = 0; kk < 16; ++kk) {
            float a[8], bb[8];
            *(float4*)&a[0]  = *(const float4*)&As[kk][tm * 8];
            *(float4*)&a[4]  = *(const float4*)&As[kk][tm * 8 + 4];
            *(float4*)&bb[0] = *(const float4*)&Bs[kk][tn * 8];
            *(float4*)&bb[4] = *(const float4*)&Bs[kk][tn * 8 + 4];
            #pragma unroll
            for (int i = 0; i < 8; ++i)
                #pragma unroll
                for (int jx = 0; jx < 8; ++jx)
                    acc[i][jx] = fmaf(a[i], bb[jx], acc[i][jx]);
        }
    }

    #pragma unroll
    for (int i = 0; i < 8; ++i) {
        float* crow = C + (M0 + tm * 8 + i) * 512 + N0 + tn * 8;
        float4 o0, o1;
        o0.x = acc[i][0] + bv[0]; o0.y = acc[i][1] + bv[1];
        o0.z = acc[i][2] + bv[2]; o0.w = acc[i][3] + bv[3];
        o1.x = acc[i][4] + bv[4]; o1.y = acc[i][5] + bv[5];
        o1.z = acc[i][6] + bv[6]; o1.w = acc[i][7] + bv[7];
        *(float4*)crow = o0;
        *((float4*)crow + 1) = o1;
    }
}

// ---------------------------------------------------------------------------
// Kernel 2: the scan. 256 blocks x 256 threads, 1 block/CU (VGPR-forced).
// Block b: g = b & 63 (batch row), s = b >> 6 (feature slice of 128).
// Group = 4 blocks of one row; blockIdx of the group are {g, g+64, g+128, g+192},
// all congruent mod 8 -> same-XCD under round-robin dispatch (perf heuristic only).
// Thread: j = tid & 127 (feature), kh = tid >> 7 (K half of 256).
// wreg[256] = W_hh[k, f0+j] for k in half -> 256 VGPRs.
// ---------------------------------------------------------------------------
__global__ __launch_bounds__(256, 1) void rnn_scan(
    const float* __restrict__ whh,   // [512, 512]
    float* __restrict__ out,         // [64, 1024, 512]; holds xp, overwritten with h
    float* __restrict__ hbuf,        // [2][64][512] double buffer
    unsigned* __restrict__ flags)    // [64] monotonic counters (memset to 0)
{
    __shared__ float hs[512];
    __shared__ float red[2][128];

    const int tid = threadIdx.x;
    const int b = blockIdx.x;
    const int g = b & 63;
    const int s = b >> 6;
    const int f0 = s * 128;
    const int j = tid & 127;
    const int kh = tid >> 7;
    const int kbase = kh * 256;

    // Load weight slice into registers (one-time).
    float wreg[256];
    {
        const float* wp = whh + (size_t)kbase * 512 + f0 + j;
        #pragma unroll
        for (int kk = 0; kk < 256; ++kk) wreg[kk] = wp[(size_t)kk * 512];
    }

    float* orow = out + (size_t)g * (RNN_T * RNN_F) + f0;
    unsigned* flag = flags + g;

    #pragma unroll 1
    for (int t = 0; t < RNN_T; ++t) {
        if (t > 0) {
            // Wait for all 4 blocks of this row to have published h_{t-1}.
            if (tid == 0) {
                const unsigned target = 4u * (unsigned)t;
                while (__hip_atomic_load(flag, __ATOMIC_RELAXED,
                                         __HIP_MEMORY_SCOPE_AGENT) < target) {
                    __builtin_amdgcn_s_sleep(1);
                }
            }
            __syncthreads();
            __builtin_amdgcn_fence(__ATOMIC_ACQUIRE, "agent");
            // Stage h_{t-1}[g, :] (2 KB) into LDS.
            if (tid < 128) {
                const float4* hp = (const float4*)(hbuf +
                    (size_t)((t + 1) & 1) * (RNN_B * RNN_F) + (size_t)g * RNN_F);
                ((float4*)hs)[tid] = hp[tid];
            }
            __syncthreads();
        }

        // xp for my output element (also overlaps MAC latency).
        float xpv = 0.f;
        if (tid < 128) xpv = orow[(size_t)t * RNN_F + j];

        float acc = 0.f;
        if (t > 0) {
            #pragma unroll
            for (int kk = 0; kk < 256; kk += 4) {
                float4 h4 = *(const float4*)&hs[kbase + kk];
                acc = fmaf(h4.x, wreg[kk + 0], acc);
                acc = fmaf(h4.y, wreg[kk + 1], acc);
                acc = fmaf(h4.z, wreg[kk + 2], acc);
                acc = fmaf(h4.w, wreg[kk + 3], acc);
            }
        }
        red[kh][j] = acc;
        __syncthreads();

        if (tid < 128) {
            float sum = red[0][j] + red[1][j];
            float val = tanhf(xpv + sum);
            hbuf[(size_t)(t & 1) * (RNN_B * RNN_F) + (size_t)g * RNN_F + f0 + j] = val;
            orow[(size_t)t * RNN_F + j] = val;
        }
        __threadfence();      // agent-scope release of h stores
        __syncthreads();      // all threads' stores fenced before publish
        if (tid == 0)
            __hip_atomic_fetch_add(flag, 1u, __ATOMIC_RELEASE,
                                   __HIP_MEMORY_SCOPE_AGENT);
    }
}

extern "C" void kernel_launch(void* const* d_in, const int* in_sizes, int n_in,
                              void* d_out, int out_size, void* d_ws, size_t ws_size,
                              hipStream_t stream) {
    const float* X    = (const float*)d_in[0];  // [64,1024,512]
    const float* Wih  = (const float*)d_in[1];  // [512,512]
    const float* Whh  = (const float*)d_in[2];  // [512,512]
    const float* bias = (const float*)d_in[3];  // [512]
    float* out = (float*)d_out;                 // [64,1024,512]

    float* hbuf = (float*)d_ws;                                   // 2*64*512 fp32 = 256 KB
    unsigned* flags = (unsigned*)((char*)d_ws + 2 * RNN_B * RNN_F * sizeof(float));

    hipMemsetAsync(flags, 0, RNN_B * sizeof(unsigned), stream);

    // x_proj into d_out
    xproj_gemm<<<dim3(2048), dim3(256), 0, stream>>>(X, Wih, bias, out);

    // sequential scan, in-place over d_out
    rnn_scan<<<dim3(256), dim3(256), 0, stream>>>(Whh, out, hbuf, flags);
}

// Round 3
// 24764.673 us; speedup vs baseline: 1.1460x; 1.1460x over previous
//
#include <hip/hip_runtime.h>
#include <hip/hip_bf16.h>

// Problem: B=64, T=1024, D=512, F=512, all fp32.
// out[b,t,:] = h_t = tanh(x_t @ W_ih + bias + h_{t-1} @ W_hh)
//
// K1: x_proj GEMM [65536,512]@[512,512]+bias -> d_out (xp buffer, overwritten
//     in-place by the scan; each slot read exactly once before overwrite).
// K2: persistent scan, 256 blocks x 256 threads.
//     Block b: r = b&15 (row-group: batch rows 4r..4r+3), s = b>>4 (cols 32s..32s+31).
//     All 16 blocks of a group are == r (mod 8) -> same XCD under round-robin
//     dispatch (PERF heuristic only; correctness does not depend on it).
//     Thread: j = tid&31 (col), kq = tid>>5 (k-chunk of 64). wreg[64] per thread.
//     h exchange: agent-scope ATOMIC loads/stores (performed at the coherence
//     point -> immune to cross-XCD L2 staleness that broke R2's plain-load path),
//     ordered by a per-group monotonic flag counter (release add / relaxed poll,
//     skew provably <= 1 step). VGPR < 256 -> all 256 blocks co-resident -> no
//     deadlock on the spin.

#define RNN_B 64
#define RNN_T 1024
#define RNN_D 512
#define RNN_F 512

// ---------------------------------------------------------------------------
// Kernel 1: x_proj = X @ W_ih + bias.  M=65536, N=512, K=512.
// ---------------------------------------------------------------------------
__global__ __launch_bounds__(256) void xproj_gemm(
    const float* __restrict__ A,     // [65536, 512]
    const float* __restrict__ W,     // [512, 512]
    const float* __restrict__ bias,  // [512]
    float* __restrict__ C)           // [65536, 512]
{
    __shared__ float As[16][132];
    __shared__ float Bs[16][132];

    const int tid = threadIdx.x;
    const int bid = blockIdx.x;
    const int mt = bid >> 2;
    const int nt = bid & 3;
    const size_t M0 = (size_t)mt * 128;
    const int N0 = nt * 128;

    const int tm = tid >> 4;
    const int tn = tid & 15;

    const int ar = tid >> 2;
    const int ac = (tid & 3) * 4;
    const int br = tid >> 5;
    const int bc = (tid & 31) * 4;

    float acc[8][8];
    #pragma unroll
    for (int i = 0; i < 8; ++i)
        #pragma unroll
        for (int jx = 0; jx < 8; ++jx) acc[i][jx] = 0.f;

    float bv[8];
    #pragma unroll
    for (int i = 0; i < 8; ++i) bv[i] = bias[N0 + tn * 8 + i];

    for (int k0 = 0; k0 < 512; k0 += 16) {
        float4 a0 = *(const float4*)(A + (M0 + ar) * 512 + k0 + ac);
        float4 a1 = *(const float4*)(A + (M0 + ar + 64) * 512 + k0 + ac);
        float4 b0 = *(const float4*)(W + (size_t)(k0 + br) * 512 + N0 + bc);
        float4 b1 = *(const float4*)(W + (size_t)(k0 + br + 8) * 512 + N0 + bc);
        __syncthreads();
        As[ac + 0][ar] = a0.x; As[ac + 1][ar] = a0.y;
        As[ac + 2][ar] = a0.z; As[ac + 3][ar] = a0.w;
        As[ac + 0][ar + 64] = a1.x; As[ac + 1][ar + 64] = a1.y;
        As[ac + 2][ar + 64] = a1.z; As[ac + 3][ar + 64] = a1.w;
        *(float4*)&Bs[br][bc]     = b0;
        *(float4*)&Bs[br + 8][bc] = b1;
        __syncthreads();
        #pragma unroll
        for (int kk = 0; kk < 16; ++kk) {
            float a[8], bb[8];
            *(float4*)&a[0]  = *(const float4*)&As[kk][tm * 8];
            *(float4*)&a[4]  = *(const float4*)&As[kk][tm * 8 + 4];
            *(float4*)&bb[0] = *(const float4*)&Bs[kk][tn * 8];
            *(float4*)&bb[4] = *(const float4*)&Bs[kk][tn * 8 + 4];
            #pragma unroll
            for (int i = 0; i < 8; ++i)
                #pragma unroll
                for (int jx = 0; jx < 8; ++jx)
                    acc[i][jx] = fmaf(a[i], bb[jx], acc[i][jx]);
        }
    }

    #pragma unroll
    for (int i = 0; i < 8; ++i) {
        float* crow = C + (M0 + tm * 8 + i) * 512 + N0 + tn * 8;
        float4 o0, o1;
        o0.x = acc[i][0] + bv[0]; o0.y = acc[i][1] + bv[1];
        o0.z = acc[i][2] + bv[2]; o0.w = acc[i][3] + bv[3];
        o1.x = acc[i][4] + bv[4]; o1.y = acc[i][5] + bv[5];
        o1.z = acc[i][6] + bv[6]; o1.w = acc[i][7] + bv[7];
        *(float4*)crow = o0;
        *((float4*)crow + 1) = o1;
    }
}

// ---------------------------------------------------------------------------
// Kernel 2: the scan.
// ---------------------------------------------------------------------------
__global__ __launch_bounds__(256, 1) void rnn_scan(
    const float* __restrict__ whh,   // [512, 512]
    float* __restrict__ out,         // [64, 1024, 512]; holds xp, overwritten with h
    float* __restrict__ hbuf,        // [2][64][512] double buffer
    unsigned* __restrict__ flags)    // [16][32] monotonic counters (memset 0)
{
    __shared__ float hs[4][512];        // h_{t-1} for my 4 rows (8 KB)
    __shared__ float red[8][4][32];     // partial sums [kq][row][col] (4 KB)

    const int tid = threadIdx.x;
    const int b = blockIdx.x;
    const int r = b & 15;            // row group 0..15 -> batch rows 4r..4r+3
    const int s = b >> 4;            // col slice 0..15 -> cols 32s..32s+31
    const int j = tid & 31;
    const int kq = tid >> 5;         // 0..7
    const int kbase = kq * 64;
    const int col = s * 32 + j;
    const int row0 = r * 4;
    const int orr = tid >> 5;        // output row role (tid<128: 0..3)

    // One-time: weight slice into registers. 64 floats/thread.
    float wreg[64];
    #pragma unroll
    for (int kk = 0; kk < 64; ++kk)
        wreg[kk] = whh[(size_t)(kbase + kk) * RNN_F + col];

    unsigned* flag = flags + r * 32;   // groups 128 B apart

    #pragma unroll 1
    for (int t = 0; t < RNN_T; ++t) {
        // Prefetch xp for my output element BEFORE the wait (overlaps spin).
        // Safe: this (row,col,t) slot is written only by THIS block, at step t.
        float xpv = 0.f;
        if (tid < 128)
            xpv = out[((size_t)(row0 + orr) * RNN_T + t) * RNN_F + col];

        if (t > 0) {
            if (tid == 0) {
                const unsigned target = 16u * (unsigned)t;
                while (__hip_atomic_load(flag, __ATOMIC_RELAXED,
                                         __HIP_MEMORY_SCOPE_AGENT) < target) {
                    __builtin_amdgcn_s_sleep(1);
                }
            }
            __syncthreads();
            __builtin_amdgcn_fence(__ATOMIC_ACQUIRE, "agent");
            // Stage h_{t-1} for rows row0..row0+3 (8 KB) into LDS with
            // agent-scope atomic 8-byte loads (coherence-point reads; the plain
            // float4 path here was the R2 cross-XCD staleness bug).
            {
                const unsigned long long* src = (const unsigned long long*)(hbuf +
                    (size_t)((t + 1) & 1) * (RNN_B * RNN_F) + (size_t)row0 * RNN_F);
                unsigned long long* dst = (unsigned long long*)&hs[0][0];
                #pragma unroll
                for (int i = 0; i < 4; ++i) {
                    dst[tid + 256 * i] = __hip_atomic_load(
                        src + tid + 256 * i, __ATOMIC_RELAXED,
                        __HIP_MEMORY_SCOPE_AGENT);
                }
            }
            __syncthreads();
        }

        float acc0 = 0.f, acc1 = 0.f, acc2 = 0.f, acc3 = 0.f;
        if (t > 0) {
            #pragma unroll
            for (int kk = 0; kk < 64; kk += 4) {
                float4 h0 = *(const float4*)&hs[0][kbase + kk];
                float4 h1 = *(const float4*)&hs[1][kbase + kk];
                float4 h2 = *(const float4*)&hs[2][kbase + kk];
                float4 h3 = *(const float4*)&hs[3][kbase + kk];
                acc0 = fmaf(h0.x, wreg[kk+0], acc0);
                acc0 = fmaf(h0.y, wreg[kk+1], acc0);
                acc0 = fmaf(h0.z, wreg[kk+2], acc0);
                acc0 = fmaf(h0.w, wreg[kk+3], acc0);
                acc1 = fmaf(h1.x, wreg[kk+0], acc1);
                acc1 = fmaf(h1.y, wreg[kk+1], acc1);
                acc1 = fmaf(h1.z, wreg[kk+2], acc1);
                acc1 = fmaf(h1.w, wreg[kk+3], acc1);
                acc2 = fmaf(h2.x, wreg[kk+0], acc2);
                acc2 = fmaf(h2.y, wreg[kk+1], acc2);
                acc2 = fmaf(h2.z, wreg[kk+2], acc2);
                acc2 = fmaf(h2.w, wreg[kk+3], acc2);
                acc3 = fmaf(h3.x, wreg[kk+0], acc3);
                acc3 = fmaf(h3.y, wreg[kk+1], acc3);
                acc3 = fmaf(h3.z, wreg[kk+2], acc3);
                acc3 = fmaf(h3.w, wreg[kk+3], acc3);
            }
        }
        red[kq][0][j] = acc0;
        red[kq][1][j] = acc1;
        red[kq][2][j] = acc2;
        red[kq][3][j] = acc3;
        __syncthreads();

        if (tid < 128) {
            float sum = 0.f;
            #pragma unroll
            for (int q = 0; q < 8; ++q) sum += red[q][orr][j];
            float val = tanhf(xpv + sum);
            out[((size_t)(row0 + orr) * RNN_T + t) * RNN_F + col] = val;
            // Agent-scope atomic store: payload performed at coherence point.
            __hip_atomic_store(
                hbuf + (size_t)(t & 1) * (RNN_B * RNN_F) +
                       (size_t)(row0 + orr) * RNN_F + col,
                val, __ATOMIC_RELAXED, __HIP_MEMORY_SCOPE_AGENT);
        }
        __builtin_amdgcn_fence(__ATOMIC_RELEASE, "agent");
        __syncthreads();   // waits vmcnt(0): h stores physically complete
        if (tid == 0)
            __hip_atomic_fetch_add(flag, 1u, __ATOMIC_RELEASE,
                                   __HIP_MEMORY_SCOPE_AGENT);
    }
}

extern "C" void kernel_launch(void* const* d_in, const int* in_sizes, int n_in,
                              void* d_out, int out_size, void* d_ws, size_t ws_size,
                              hipStream_t stream) {
    const float* X    = (const float*)d_in[0];  // [64,1024,512]
    const float* Wih  = (const float*)d_in[1];  // [512,512]
    const float* Whh  = (const float*)d_in[2];  // [512,512]
    const float* bias = (const float*)d_in[3];  // [512]
    float* out = (float*)d_out;                 // [64,1024,512]

    float* hbuf = (float*)d_ws;                 // 2*64*512 fp32 = 256 KB
    unsigned* flags = (unsigned*)((char*)d_ws + 2 * RNN_B * RNN_F * sizeof(float));

    hipMemsetAsync(flags, 0, 16 * 32 * sizeof(unsigned), stream);

    xproj_gemm<<<dim3(2048), dim3(256), 0, stream>>>(X, Wih, bias, out);
    rnn_scan<<<dim3(256), dim3(256), 0, stream>>>(Whh, out, hbuf, flags);
}